// Round 10
// baseline (20.807 us; speedup 1.0000x reference)
//
#include <hip/hip_runtime.h>
#include <stdint.h>

#define H 512
#define W 512
#define B 8
#define TW 32
#define TILEH 32
#define NBX (W / TW)          // 16
#define NBY (H / TILEH)       // 16
#define NBLK (NBX * NBY * B)  // 2048

// R9 structure + issue-count trims:
//  - alignbit single-op window extraction from 64-bit row masks
//  - packed u32 indicator accumulator (t1 | bm<<10 | ok<<20), no stat ballots
//  - row-validity bitmask precomputed in phase 1
//  phase 1: T halo loads -> regs; phase 2: preds float4 loads; phase 3: ballot
//  chain (41 lanes, mask=ballot>>1); nearlut[512]; wlut[26]; 2-exp softmax;
//  shuffle reduce -> 7 per-block partials. No atomics.
__global__ __launch_bounds__(256) void seg_main(const float* __restrict__ preds,
                                                const int* __restrict__ tgt,
                                                float* __restrict__ partials) {
    __shared__ unsigned long long emask[40];   // rows by0-4 .. by0+35; bit c <-> col bx0-4+c
    __shared__ unsigned char tileT[32][32];    // target classes of the owned tile
    __shared__ unsigned char nearlut[512];     // 9-bit window -> min(ax^2, 25)
    __shared__ float wlut[26];                 // d2min -> weight
    __shared__ float redf[4][4];
    __shared__ unsigned int redc[4];

    const int lx = threadIdx.x;  // 0..31
    const int ly = threadIdx.y;  // 0..7
    const int tid = ly * 32 + lx;
    const int wave = tid >> 6;
    const int lane = tid & 63;

    const int bx0 = blockIdx.x * TW;
    const int by0 = blockIdx.y * TILEH;
    const int b = blockIdx.z;
    const int blk = blockIdx.x + NBX * (blockIdx.y + NBY * blockIdx.z);

    const int* T = tgt + (size_t)b * H * W;
    const float* Pb = preds + (size_t)b * 3 * H * W;

    // ---- phase 1: T halo loads into registers (all independent) ----
    const int ex = bx0 - 5 + lane;              // lanes 0..40 cover cols bx0-5..bx0+35
    const bool xok = (lane <= 40) & (ex >= 0) & (ex < W);
    const int r0 = wave * 10;
    const int ey0 = by0 - 4 + r0;
    int trow[10];
    unsigned int vmask = 0;                     // bit i: row i valid for this lane
    int tup0 = 0;
    if (xok && (ey0 - 1) >= 0) tup0 = T[(size_t)(ey0 - 1) * W + ex];
    #pragma unroll
    for (int i = 0; i < 10; ++i) {
        const int ey = ey0 + i;
        const bool rok = xok & (ey >= 0) & (ey < H);
        trow[i] = rok ? T[(size_t)ey * W + ex] : 0;
        vmask |= rok ? (1u << i) : 0u;
    }

    // ---- phase 2: preds loads (latency hides under ballot chain) ----
    const int g = lx & 7;               // column group: cols 4g..4g+3
    const int row = ly * 4 + (lx >> 3); // tile row 0..31
    const int gy = by0 + row;
    const int gx0 = bx0 + 4 * g;
    const size_t pix = (size_t)gy * W + gx0;
    const float4 q0 = *(const float4*)(Pb + pix);
    const float4 q1 = *(const float4*)(Pb + pix + (size_t)H * W);
    const float4 q2 = *(const float4*)(Pb + pix + (size_t)2 * H * W);

    // ---- fill LUTs ----
    #pragma unroll
    for (int k = 0; k < 2; ++k) {
        const int idx = tid + 256 * k;
        unsigned int u = (((unsigned)idx >> 4) & 31u) |
                         (__brev((unsigned)idx & 31u) >> 27) | 0x20u;
        int ax = __ffs(u) - 1;
        nearlut[idx] = (unsigned char)min(ax * ax, 25);
    }
    if (tid < 26)
        wlut[tid] = (tid >= 25) ? 1.0f : (2.0f - sqrtf((float)tid) * 0.2f);

    // ---- phase 3: ballot chain from registers, stash tile classes ----
    {
        const bool exok = (ex > 0);
        int tup = tup0;
        #pragma unroll
        for (int i = 0; i < 10; ++i) {
            const int r = r0 + i;
            int t0 = trow[i];
            int tl = __shfl_up(t0, 1, 64);
            bool e = ((vmask >> i) & 1u) &
                     ((((ey0 + i > 0) & (t0 != tup))) | ((exok & (t0 != tl))));
            unsigned long long m = __ballot(e) >> 1;   // bit c <-> col bx0-4+c
            if (lane == 0) emask[r] = m;
            if ((r >= 4) & (r < 36) & (lane >= 5) & (lane <= 36))
                tileT[r - 4][lane - 5] = (unsigned char)t0;
            tup = t0;
        }
    }
    __syncthreads();

    const uchar4 tt = *(const uchar4*)&tileT[row][4 * g];

    unsigned long long rowm[5];
    rowm[0] = emask[row + 4];
    #pragma unroll
    for (int a = 1; a <= 4; ++a) rowm[a] = emask[row + 4 + a] | emask[row + 4 - a];

    const unsigned int allowA[5] = {0x1FFu, 0x1FFu, 0x1FFu, 0xFEu, 0x7Cu};
    const int a2c[5] = {0, 1, 4, 9, 16};

    float s0 = 0.f, s1 = 0.f, s2 = 0.f, s3 = 0.f;  // ce*w, p1*t1, p1, w
    unsigned int cnt = 0;                          // t1 | bm<<10 | ok<<20

    #pragma unroll
    for (int c = 0; c < 4; ++c) {
        const int px = 4 * g + c;
        int d2min = 25;
        #pragma unroll
        for (int a = 0; a < 5; ++a) {
            unsigned int bb = __builtin_amdgcn_alignbit(
                (unsigned int)(rowm[a] >> 32), (unsigned int)rowm[a],
                (unsigned int)px) & allowA[a];
            d2min = min(d2min, a2c[a] + (int)nearlut[bb]);
        }
        const float wgt = wlut[d2min];

        const int t = (c == 0) ? tt.x : ((c == 1) ? tt.y : ((c == 2) ? tt.z : tt.w));
        const float p0 = (c == 0) ? q0.x : ((c == 1) ? q0.y : ((c == 2) ? q0.z : q0.w));
        const float p1 = (c == 0) ? q1.x : ((c == 1) ? q1.y : ((c == 2) ? q1.z : q1.w));
        const float p2 = (c == 0) ? q2.x : ((c == 1) ? q2.y : ((c == 2) ? q2.z : q2.w));

        // 2-exp softmax relative to p1 (inputs ~N(0,1), no overflow risk):
        float e0 = __expf(p0 - p1), e2 = __expf(p2 - p1);
        float sp = e0 + 1.0f + e2;
        float lse = p1 + __logf(sp);
        float pt = (t == 0) ? p0 : ((t == 1) ? p1 : p2);
        float ce = lse - pt;
        float prob1 = __builtin_amdgcn_rcpf(sp);

        int cls = 0;
        float best = p0;
        if (p1 > best) { best = p1; cls = 1; }
        if (p2 > best) { cls = 2; }

        const bool ist1 = (t == 1);
        const bool bm = wgt > 1.5f;
        cnt += (ist1 ? 1u : 0u) + (bm ? (1u << 10) : 0u) +
               ((bm & (cls == t)) ? (1u << 20) : 0u);

        s0 += ce * wgt;
        s1 += ist1 ? prob1 : 0.0f;
        s2 += prob1;
        s3 += wgt;
    }

    #pragma unroll
    for (int off = 32; off >= 1; off >>= 1) {
        s0 += __shfl_down(s0, off, 64);
        s1 += __shfl_down(s1, off, 64);
        s2 += __shfl_down(s2, off, 64);
        s3 += __shfl_down(s3, off, 64);
        cnt += __shfl_down(cnt, off, 64);
    }
    if (lane == 0) {
        redf[wave][0] = s0; redf[wave][1] = s1; redf[wave][2] = s2; redf[wave][3] = s3;
        redc[wave] = cnt;
    }
    __syncthreads();
    if (tid == 0) {
        float f0 = redf[0][0] + redf[1][0] + redf[2][0] + redf[3][0];
        float f1 = redf[0][1] + redf[1][1] + redf[2][1] + redf[3][1];
        float f2 = redf[0][2] + redf[1][2] + redf[2][2] + redf[3][2];
        float f3 = redf[0][3] + redf[1][3] + redf[2][3] + redf[3][3];
        unsigned int i0 = 0, i1 = 0, i2 = 0;
        #pragma unroll
        for (int wv = 0; wv < 4; ++wv) {
            unsigned int cv = redc[wv];
            i0 += cv & 0x3FFu;
            i1 += (cv >> 10) & 0x3FFu;
            i2 += cv >> 20;
        }
        partials[0 * NBLK + blk] = f0;          // sum ce*w
        partials[1 * NBLK + blk] = f1;          // sum p1*t1
        partials[2 * NBLK + blk] = f2;          // sum p1
        partials[3 * NBLK + blk] = (float)i0;   // sum t1
        partials[4 * NBLK + blk] = f3;          // sum w
        partials[5 * NBLK + blk] = (float)i1;   // cnt
        partials[6 * NBLK + blk] = (float)i2;   // correct
    }
}

__global__ __launch_bounds__(256) void seg_final(const float* __restrict__ partials,
                                                 float* __restrict__ out) {
    __shared__ double red[4][7];
    const int tid = threadIdx.x;
    const int wave = tid >> 6, lane = tid & 63;

    // 2048 floats per quantity = 512 float4; 256 threads x 2 float4 each.
    const float4* p4 = (const float4*)partials;
    float4 va[7], vb[7];
    #pragma unroll
    for (int k = 0; k < 7; ++k) {
        va[k] = p4[k * 512 + tid];
        vb[k] = p4[k * 512 + 256 + tid];
    }
    double s[7];
    #pragma unroll
    for (int k = 0; k < 7; ++k)
        s[k] = (((double)va[k].x + va[k].y) + ((double)va[k].z + va[k].w)) +
               (((double)vb[k].x + vb[k].y) + ((double)vb[k].z + vb[k].w));

    #pragma unroll
    for (int off = 32; off >= 1; off >>= 1) {
        #pragma unroll
        for (int k = 0; k < 7; ++k) s[k] += __shfl_down(s[k], off, 64);
    }
    if (lane == 0) {
        #pragma unroll
        for (int k = 0; k < 7; ++k) red[wave][k] = s[k];
    }
    __syncthreads();
    if (tid == 0) {
        double f[7];
        #pragma unroll
        for (int k = 0; k < 7; ++k)
            f[k] = red[0][k] + red[1][k] + red[2][k] + red[3][k];
        const double N = (double)B * H * W;
        double wce = f[0] / N;
        double dice = (2.0 * f[1] + 1.0) / (f[2] + f[3] + 1.0);
        double dl = 1.0 - dice;
        double bacc = (f[5] > 0.0) ? (f[6] / f[5]) : 0.0;
        double aw = f[4] / N;
        out[0] = (float)(wce + dl);
        out[1] = (float)wce;
        out[2] = (float)dl;
        out[3] = (float)bacc;
        out[4] = (float)aw;
    }
}

extern "C" void kernel_launch(void* const* d_in, const int* in_sizes, int n_in,
                              void* d_out, int out_size, void* d_ws, size_t ws_size,
                              hipStream_t stream) {
    const float* preds = (const float*)d_in[0];
    const int* tgt = (const int*)d_in[1];
    float* partials = (float*)d_ws;  // needs 7 * 2048 * 4 = 57,344 bytes

    dim3 grid(NBX, NBY, B);
    dim3 block(TW, 8);
    seg_main<<<grid, block, 0, stream>>>(preds, tgt, partials);
    seg_final<<<1, 256, 0, stream>>>(partials, (float*)d_out);
}

// Round 11
// 20.238 us; speedup vs baseline: 1.0281x; 1.0281x over previous
//
#include <hip/hip_runtime.h>
#include <stdint.h>

#define H 512
#define W 512
#define B 8
#define TW 32
#define TILEH 32
#define NBX (W / TW)          // 16
#define NBY (H / TILEH)       // 16
#define NBLK (NBX * NBY * B)  // 2048

// R9 (best measured: 20.37 us) — final kernel.
//  phase 1: all T halo loads -> register array (independent, issued first)
//  phase 2: preds float4 loads (complete under ballot work, NOT in chain path)
//  phase 3: ballot chain from registers (41 active lanes, mask = ballot>>1)
//  nearlut[512] 9-bit window -> capped ax^2; wlut[26] d2 -> weight
//  2-exp softmax (sp = e^(p0-p1)+1+e^(p2-p1)); ballot+popc indicators;
//  shuffle reduce -> 7 per-block partials. No atomics.
__global__ __launch_bounds__(256) void seg_main(const float* __restrict__ preds,
                                                const int* __restrict__ tgt,
                                                float* __restrict__ partials) {
    __shared__ unsigned long long emask[40];   // rows by0-4 .. by0+35; bit c <-> col bx0-4+c
    __shared__ unsigned char tileT[32][32];    // target classes of the owned tile
    __shared__ unsigned char nearlut[512];     // 9-bit window -> min(ax^2, 25)
    __shared__ float wlut[26];                 // d2min -> weight
    __shared__ float redf[4][4];
    __shared__ int redi[4][3];

    const int lx = threadIdx.x;  // 0..31
    const int ly = threadIdx.y;  // 0..7
    const int tid = ly * 32 + lx;
    const int wave = tid >> 6;
    const int lane = tid & 63;

    const int bx0 = blockIdx.x * TW;
    const int by0 = blockIdx.y * TILEH;
    const int b = blockIdx.z;
    const int blk = blockIdx.x + NBX * (blockIdx.y + NBY * blockIdx.z);

    const int* T = tgt + (size_t)b * H * W;
    const float* Pb = preds + (size_t)b * 3 * H * W;

    // ---- phase 1: T halo loads into registers (all independent) ----
    const int ex = bx0 - 5 + lane;              // lanes 0..40 cover cols bx0-5..bx0+35
    const bool xok = (lane <= 40) & (ex >= 0) & (ex < W);
    const int r0 = wave * 10;
    const int ey0 = by0 - 4 + r0;
    int trow[10];
    int tup0 = 0;
    if (xok && (ey0 - 1) >= 0) tup0 = T[(size_t)(ey0 - 1) * W + ex];
    #pragma unroll
    for (int i = 0; i < 10; ++i) {
        const int ey = ey0 + i;
        const bool rok = xok & (ey >= 0) & (ey < H);
        trow[i] = rok ? T[(size_t)ey * W + ex] : 0;
    }

    // ---- phase 2: preds loads (latency hides under ballot chain) ----
    const int g = lx & 7;               // column group: cols 4g..4g+3
    const int row = ly * 4 + (lx >> 3); // tile row 0..31
    const int gy = by0 + row;
    const int gx0 = bx0 + 4 * g;
    const size_t pix = (size_t)gy * W + gx0;
    const float4 q0 = *(const float4*)(Pb + pix);
    const float4 q1 = *(const float4*)(Pb + pix + (size_t)H * W);
    const float4 q2 = *(const float4*)(Pb + pix + (size_t)2 * H * W);

    // ---- fill LUTs ----
    #pragma unroll
    for (int k = 0; k < 2; ++k) {
        const int idx = tid + 256 * k;
        unsigned int u = (((unsigned)idx >> 4) & 31u) |
                         (__brev((unsigned)idx & 31u) >> 27) | 0x20u;
        int ax = __ffs(u) - 1;
        nearlut[idx] = (unsigned char)min(ax * ax, 25);
    }
    if (tid < 26)
        wlut[tid] = (tid >= 25) ? 1.0f : (2.0f - sqrtf((float)tid) * 0.2f);

    // ---- phase 3: ballot chain from registers, stash tile classes ----
    {
        int tup = tup0;
        #pragma unroll
        for (int i = 0; i < 10; ++i) {
            const int r = r0 + i;
            const int ey = ey0 + i;
            int t0 = trow[i];
            int tl = __shfl_up(t0, 1, 64);
            bool e = xok & (ey >= 0) & (ey < H) &
                     ((((ey > 0) & (t0 != tup))) | (((ex > 0) & (t0 != tl))));
            unsigned long long m = __ballot(e) >> 1;   // bit c <-> col bx0-4+c
            if (lane == 0) emask[r] = m;
            if ((r >= 4) & (r < 36) & (lane >= 5) & (lane <= 36))
                tileT[r - 4][lane - 5] = (unsigned char)t0;
            tup = t0;
        }
    }
    __syncthreads();

    const uchar4 tt = *(const uchar4*)&tileT[row][4 * g];

    unsigned long long rowm[5];
    rowm[0] = emask[row + 4];
    #pragma unroll
    for (int a = 1; a <= 4; ++a) rowm[a] = emask[row + 4 + a] | emask[row + 4 - a];

    const unsigned int allowA[5] = {0x1FFu, 0x1FFu, 0x1FFu, 0xFEu, 0x7Cu};
    const int a2c[5] = {0, 1, 4, 9, 16};

    float s0 = 0.f, s1 = 0.f, s2 = 0.f, s3 = 0.f;  // ce*w, p1*t1, p1, w
    int c_t1 = 0, c_bm = 0, c_ok = 0;

    #pragma unroll
    for (int c = 0; c < 4; ++c) {
        const int px = 4 * g + c;
        int d2min = 25;
        #pragma unroll
        for (int a = 0; a < 5; ++a) {
            unsigned int bb = (unsigned int)(rowm[a] >> px) & allowA[a];
            d2min = min(d2min, a2c[a] + (int)nearlut[bb]);
        }
        const float wgt = wlut[d2min];

        const int t = (c == 0) ? tt.x : ((c == 1) ? tt.y : ((c == 2) ? tt.z : tt.w));
        const float p0 = (c == 0) ? q0.x : ((c == 1) ? q0.y : ((c == 2) ? q0.z : q0.w));
        const float p1 = (c == 0) ? q1.x : ((c == 1) ? q1.y : ((c == 2) ? q1.z : q1.w));
        const float p2 = (c == 0) ? q2.x : ((c == 1) ? q2.y : ((c == 2) ? q2.z : q2.w));

        // 2-exp softmax relative to p1 (inputs ~N(0,1), no overflow risk):
        // sp = e^(p0-p1) + 1 + e^(p2-p1); lse = p1 + log(sp); prob1 = 1/sp
        float e0 = __expf(p0 - p1), e2 = __expf(p2 - p1);
        float sp = e0 + 1.0f + e2;
        float lse = p1 + __logf(sp);
        float pt = (t == 0) ? p0 : ((t == 1) ? p1 : p2);
        float ce = lse - pt;
        float prob1 = __builtin_amdgcn_rcpf(sp);

        int cls = 0;
        float best = p0;
        if (p1 > best) { best = p1; cls = 1; }
        if (p2 > best) { cls = 2; }

        bool bm = wgt > 1.5f;
        bool ok = bm & (cls == t);
        c_t1 += __popcll(__ballot(t == 1));
        c_bm += __popcll(__ballot(bm));
        c_ok += __popcll(__ballot(ok));

        s0 += ce * wgt;
        s1 += (t == 1) ? prob1 : 0.0f;
        s2 += prob1;
        s3 += wgt;
    }

    #pragma unroll
    for (int off = 32; off >= 1; off >>= 1) {
        s0 += __shfl_down(s0, off, 64);
        s1 += __shfl_down(s1, off, 64);
        s2 += __shfl_down(s2, off, 64);
        s3 += __shfl_down(s3, off, 64);
    }
    if (lane == 0) {
        redf[wave][0] = s0; redf[wave][1] = s1; redf[wave][2] = s2; redf[wave][3] = s3;
        redi[wave][0] = c_t1; redi[wave][1] = c_bm; redi[wave][2] = c_ok;
    }
    __syncthreads();
    if (tid == 0) {
        float f0 = redf[0][0] + redf[1][0] + redf[2][0] + redf[3][0];
        float f1 = redf[0][1] + redf[1][1] + redf[2][1] + redf[3][1];
        float f2 = redf[0][2] + redf[1][2] + redf[2][2] + redf[3][2];
        float f3 = redf[0][3] + redf[1][3] + redf[2][3] + redf[3][3];
        int i0 = redi[0][0] + redi[1][0] + redi[2][0] + redi[3][0];
        int i1 = redi[0][1] + redi[1][1] + redi[2][1] + redi[3][1];
        int i2 = redi[0][2] + redi[1][2] + redi[2][2] + redi[3][2];
        partials[0 * NBLK + blk] = f0;          // sum ce*w
        partials[1 * NBLK + blk] = f1;          // sum p1*t1
        partials[2 * NBLK + blk] = f2;          // sum p1
        partials[3 * NBLK + blk] = (float)i0;   // sum t1
        partials[4 * NBLK + blk] = f3;          // sum w
        partials[5 * NBLK + blk] = (float)i1;   // cnt
        partials[6 * NBLK + blk] = (float)i2;   // correct
    }
}

__global__ __launch_bounds__(256) void seg_final(const float* __restrict__ partials,
                                                 float* __restrict__ out) {
    __shared__ double red[4][7];
    const int tid = threadIdx.x;
    const int wave = tid >> 6, lane = tid & 63;

    // 2048 floats per quantity = 512 float4; 256 threads x 2 float4 each.
    const float4* p4 = (const float4*)partials;
    float4 va[7], vb[7];
    #pragma unroll
    for (int k = 0; k < 7; ++k) {
        va[k] = p4[k * 512 + tid];
        vb[k] = p4[k * 512 + 256 + tid];
    }
    double s[7];
    #pragma unroll
    for (int k = 0; k < 7; ++k)
        s[k] = (((double)va[k].x + va[k].y) + ((double)va[k].z + va[k].w)) +
               (((double)vb[k].x + vb[k].y) + ((double)vb[k].z + vb[k].w));

    #pragma unroll
    for (int off = 32; off >= 1; off >>= 1) {
        #pragma unroll
        for (int k = 0; k < 7; ++k) s[k] += __shfl_down(s[k], off, 64);
    }
    if (lane == 0) {
        #pragma unroll
        for (int k = 0; k < 7; ++k) red[wave][k] = s[k];
    }
    __syncthreads();
    if (tid == 0) {
        double f[7];
        #pragma unroll
        for (int k = 0; k < 7; ++k)
            f[k] = red[0][k] + red[1][k] + red[2][k] + red[3][k];
        const double N = (double)B * H * W;
        double wce = f[0] / N;
        double dice = (2.0 * f[1] + 1.0) / (f[2] + f[3] + 1.0);
        double dl = 1.0 - dice;
        double bacc = (f[5] > 0.0) ? (f[6] / f[5]) : 0.0;
        double aw = f[4] / N;
        out[0] = (float)(wce + dl);
        out[1] = (float)wce;
        out[2] = (float)dl;
        out[3] = (float)bacc;
        out[4] = (float)aw;
    }
}

extern "C" void kernel_launch(void* const* d_in, const int* in_sizes, int n_in,
                              void* d_out, int out_size, void* d_ws, size_t ws_size,
                              hipStream_t stream) {
    const float* preds = (const float*)d_in[0];
    const int* tgt = (const int*)d_in[1];
    float* partials = (float*)d_ws;  // needs 7 * 2048 * 4 = 57,344 bytes

    dim3 grid(NBX, NBY, B);
    dim3 block(TW, 8);
    seg_main<<<grid, block, 0, stream>>>(preds, tgt, partials);
    seg_final<<<1, 256, 0, stream>>>(partials, (float*)d_out);
}